// Round 5
// baseline (900.785 us; speedup 1.0000x reference)
//
#include <hip/hip_runtime.h>
#include <cstdint>
#include <cstddef>

#define NFEAT 500
#define NHID  128
#define NCLASS 40

typedef __attribute__((ext_vector_type(8))) short bf16x8;
typedef __attribute__((ext_vector_type(4))) float f32x4;

__device__ __forceinline__ unsigned short f2bf(float f) {
    union { float f; unsigned u; } v; v.f = f;
    unsigned u = v.u;
    unsigned r = u + 0x7FFF + ((u >> 16) & 1);   // round-to-nearest-even
    return (unsigned short)(r >> 16);
}
__device__ __forceinline__ float bf2f(unsigned short h) {
    union { unsigned u; float f; } v; v.u = ((unsigned)h) << 16; return v.f;
}

// ---------------- CSR construction ----------------

__global__ void k_hist(const int* __restrict__ row, int E, int* __restrict__ counts) {
    int i = blockIdx.x * 256 + threadIdx.x;
    if (i < E) atomicAdd(&counts[row[i]], 1);
}

__global__ void k_block_sum(const int* __restrict__ counts, int n, int* __restrict__ partials) {
    __shared__ int tmp[256];
    int i = blockIdx.x * 256 + threadIdx.x;
    tmp[threadIdx.x] = (i < n) ? counts[i] : 0;
    __syncthreads();
    for (int o = 128; o > 0; o >>= 1) {
        if (threadIdx.x < o) tmp[threadIdx.x] += tmp[threadIdx.x + o];
        __syncthreads();
    }
    if (threadIdx.x == 0) partials[blockIdx.x] = tmp[0];
}

__global__ void k_scan_partials(int* __restrict__ partials, int nb) {
    __shared__ int tmp[512];
    int t = threadIdx.x;
    int v = (t < nb) ? partials[t] : 0;
    tmp[t] = v;
    __syncthreads();
    for (int o = 1; o < 512; o <<= 1) {
        int add = (t >= o) ? tmp[t - o] : 0;
        __syncthreads();
        tmp[t] += add;
        __syncthreads();
    }
    if (t < nb) partials[t] = tmp[t] - v;   // exclusive
}

// also zeroes counts for reuse as cursor
__global__ void k_scan_counts(int* __restrict__ counts, const int* __restrict__ partials,
                              int* __restrict__ row_ptr, int n) {
    __shared__ int tmp[256];
    int t = threadIdx.x;
    int i = blockIdx.x * 256 + t;
    int v = (i < n) ? counts[i] : 0;
    tmp[t] = v;
    __syncthreads();
    for (int o = 1; o < 256; o <<= 1) {
        int add = (t >= o) ? tmp[t - o] : 0;
        __syncthreads();
        tmp[t] += add;
        __syncthreads();
    }
    int incl = tmp[t];
    int base = partials[blockIdx.x];
    if (i < n) {
        row_ptr[i] = base + incl - v;
        counts[i] = 0;
    }
    if (i == n - 1) row_ptr[n] = base + incl;
}

__global__ void k_scatter(const int* __restrict__ row, const int* __restrict__ col,
                          const float* __restrict__ w, int E,
                          const int* __restrict__ row_ptr, int* __restrict__ cursor,
                          uint2* __restrict__ csr_cw) {
    int i = blockIdx.x * 256 + threadIdx.x;
    if (i < E) {
        int r = row[i];
        int p = row_ptr[r] + atomicAdd(&cursor[r], 1);
        csr_cw[p] = make_uint2((unsigned)col[i], __float_as_uint(w[i]));
    }
}

// ---------------- weight prep: W[K][N] fp32 -> Wt[Nt][Kpad] bf16 (transposed, zero-padded) ----------------

__global__ void k_prep_w(const float* __restrict__ W, unsigned short* __restrict__ Wt,
                         int K, int Norig, int Nt, int Kpad) {
    int idx = blockIdx.x * 256 + threadIdx.x;
    if (idx >= Nt * Kpad) return;
    int n = idx / Kpad, k = idx % Kpad;
    unsigned short v = 0;
    if (k < K && n < Norig) v = f2bf(W[(size_t)k * Norig + n]);
    Wt[idx] = v;
}

// ---------------- MFMA GEMM: C[M][CPITCH] = A[M][K] @ Wt^T, bf16 out, fp32 acc ----------------
// BM=64, BK=32, 256 threads (4 waves). Register-prefetch pipeline: loads for tile k+1
// issue right after the post-store barrier, overlapping the ds_read+MFMA phase of tile k.
// BN=128: wave grid 2x2 (32x64 per wave, TM=2 TN=4). BN=48: 4x1 (16x48, TM=1 TN=3).
// bf16-A buffers are padded to Mpad rows -> no M guards; fp32-A (layer 1) guards gm<M.

template<bool AFP32, int BN, int CN, int CPITCH>
__global__ __launch_bounds__(256) void k_gemm_mfma(const void* __restrict__ Ain,
                                                   const unsigned short* __restrict__ Wt,
                                                   unsigned short* __restrict__ C,
                                                   int M, int K, int Kpad) {
    constexpr int P  = 40;                     // LDS pitch (ushorts) = 80 B
    constexpr int NW = (BN == 128) ? 2 : 1;
    constexpr int MW = 4 / NW;
    constexpr int TM = 64 / (MW * 16);
    constexpr int TN = BN / (NW * 16);
    constexpr int WCH = (BN == 128) ? 2 : 1;   // W staging chunks per thread
    __shared__ unsigned short As[64][P];
    __shared__ unsigned short Ws[BN][P];

    const int t = threadIdx.x;
    const int lane = t & 63;
    const int w = t >> 6;
    const int wm = w / NW, wn = w % NW;
    const int mbase = blockIdx.x * 64;
    const int l15 = lane & 15, quad = lane >> 4;

    const float* Af = (const float*)Ain;
    const unsigned short* Ab = (const unsigned short*)Ain;

    f32x4 acc[TM][TN];
#pragma unroll
    for (int mi = 0; mi < TM; mi++)
#pragma unroll
        for (int ni = 0; ni < TN; ni++)
            acc[mi][ni] = (f32x4){0.f, 0.f, 0.f, 0.f};

    // staging registers
    float4 ra_f[2];
    uint4  ra_b;
    uint4  rw[WCH];

    auto loadA = [&](int k0) {
        if (AFP32) {
#pragma unroll
            for (int p = 0; p < 2; p++) {
                int idx = p * 256 + t;
                int m = idx >> 3, ch = idx & 7;
                int gm = mbase + m, gk = k0 + ch * 4;
                float4 v = make_float4(0.f, 0.f, 0.f, 0.f);
                if (gm < M && gk < K) v = *(const float4*)(Af + (size_t)gm * K + gk);
                ra_f[p] = v;
            }
        } else {
            int m = t >> 2, ch = t & 3;
            ra_b = *(const uint4*)(Ab + (size_t)(mbase + m) * Kpad + k0 + ch * 8);
        }
    };
    auto loadW = [&](int k0) {
#pragma unroll
        for (int p = 0; p < WCH; p++) {
            int idx = p * 256 + t;
            if (BN * 4 > idx) {
                int n = idx >> 2, ch = idx & 3;
                rw[p] = *(const uint4*)(Wt + (size_t)n * Kpad + k0 + ch * 8);
            }
        }
    };
    auto storeLDS = [&]() {
        if (AFP32) {
#pragma unroll
            for (int p = 0; p < 2; p++) {
                int idx = p * 256 + t;
                int m = idx >> 3, ch = idx & 7;
                float4 v = ra_f[p];
                unsigned long long pk = (unsigned long long)f2bf(v.x)
                                      | ((unsigned long long)f2bf(v.y) << 16)
                                      | ((unsigned long long)f2bf(v.z) << 32)
                                      | ((unsigned long long)f2bf(v.w) << 48);
                *(unsigned long long*)&As[m][ch * 4] = pk;
            }
        } else {
            int m = t >> 2, ch = t & 3;
            *(uint4*)&As[m][ch * 8] = ra_b;
        }
#pragma unroll
        for (int p = 0; p < WCH; p++) {
            int idx = p * 256 + t;
            if (BN * 4 > idx) {
                int n = idx >> 2, ch = idx & 3;
                *(uint4*)&Ws[n][ch * 8] = rw[p];
            }
        }
    };

    loadA(0);
    loadW(0);
    for (int k0 = 0; k0 < Kpad; k0 += 32) {
        storeLDS();
        __syncthreads();
        bool more = (k0 + 32) < Kpad;
        if (more) {                 // prefetch next tile; overlaps MFMA below
            loadA(k0 + 32);
            loadW(k0 + 32);
        }
        bf16x8 afr[TM], bfr[TN];
#pragma unroll
        for (int mi = 0; mi < TM; mi++)
            afr[mi] = *(const bf16x8*)&As[wm * (TM * 16) + mi * 16 + l15][quad * 8];
#pragma unroll
        for (int ni = 0; ni < TN; ni++)
            bfr[ni] = *(const bf16x8*)&Ws[wn * (TN * 16) + ni * 16 + l15][quad * 8];
#pragma unroll
        for (int mi = 0; mi < TM; mi++)
#pragma unroll
            for (int ni = 0; ni < TN; ni++)
                acc[mi][ni] = __builtin_amdgcn_mfma_f32_16x16x32_bf16(afr[mi], bfr[ni], acc[mi][ni], 0, 0, 0);
        if (more) __syncthreads();
    }

    // epilogue: C/D layout col=lane&15, row=quad*4+reg
#pragma unroll
    for (int mi = 0; mi < TM; mi++) {
#pragma unroll
        for (int r = 0; r < 4; r++) {
            int gm = mbase + wm * (TM * 16) + mi * 16 + quad * 4 + r;
#pragma unroll
            for (int ni = 0; ni < TN; ni++) {
                int gn = wn * (TN * 16) + ni * 16 + l15;
                if (gn < CN) C[(size_t)gm * CPITCH + gn] = f2bf(acc[mi][ni][r]);
            }
        }
    }
}

// ---------------- SpMM (width 128, bf16) + bias + optional ReLU ----------------

__global__ __launch_bounds__(256) void k_spmm128(const unsigned short* __restrict__ S,
                                                 const int* __restrict__ rp,
                                                 const uint2* __restrict__ cw,
                                                 const float* __restrict__ bias,
                                                 unsigned short* __restrict__ out,
                                                 int n, int do_relu) {
    int wid  = threadIdx.x >> 6;
    int lane = threadIdx.x & 63;
    int node = blockIdx.x * 4 + wid;
    if (node >= n) return;
    int s = rp[node], e = rp[node + 1];
    float a0x = 0.f, a0y = 0.f, a1x = 0.f, a1y = 0.f;
    float a2x = 0.f, a2y = 0.f, a3x = 0.f, a3y = 0.f;
    int i = s;
    for (; i + 4 <= e; i += 4) {
        uint2 e0 = cw[i], e1 = cw[i + 1], e2 = cw[i + 2], e3 = cw[i + 3];
        unsigned v0 = ((const unsigned*)(S + (size_t)e0.x * NHID))[lane];
        unsigned v1 = ((const unsigned*)(S + (size_t)e1.x * NHID))[lane];
        unsigned v2 = ((const unsigned*)(S + (size_t)e2.x * NHID))[lane];
        unsigned v3 = ((const unsigned*)(S + (size_t)e3.x * NHID))[lane];
        float w0 = __uint_as_float(e0.y), w1 = __uint_as_float(e1.y);
        float w2 = __uint_as_float(e2.y), w3 = __uint_as_float(e3.y);
        a0x = fmaf(w0, bf2f((unsigned short)v0), a0x); a0y = fmaf(w0, bf2f((unsigned short)(v0 >> 16)), a0y);
        a1x = fmaf(w1, bf2f((unsigned short)v1), a1x); a1y = fmaf(w1, bf2f((unsigned short)(v1 >> 16)), a1y);
        a2x = fmaf(w2, bf2f((unsigned short)v2), a2x); a2y = fmaf(w2, bf2f((unsigned short)(v2 >> 16)), a2y);
        a3x = fmaf(w3, bf2f((unsigned short)v3), a3x); a3y = fmaf(w3, bf2f((unsigned short)(v3 >> 16)), a3y);
    }
    for (; i < e; i++) {
        uint2 e0 = cw[i];
        unsigned v0 = ((const unsigned*)(S + (size_t)e0.x * NHID))[lane];
        float w0 = __uint_as_float(e0.y);
        a0x = fmaf(w0, bf2f((unsigned short)v0), a0x); a0y = fmaf(w0, bf2f((unsigned short)(v0 >> 16)), a0y);
    }
    float ax = (a0x + a1x) + (a2x + a3x) + bias[lane * 2];
    float ay = (a0y + a1y) + (a2y + a3y) + bias[lane * 2 + 1];
    if (do_relu) {
        ax = fmaxf(ax, 0.f);
        ay = fmaxf(ay, 0.f);
    }
    unsigned o = (unsigned)f2bf(ax) | ((unsigned)f2bf(ay) << 16);
    __builtin_nontemporal_store(o, (unsigned*)(out + (size_t)node * NHID) + lane);
}

// ---------------- SpMM (width 40, bf16 pitch 40) + bias + log_softmax -> fp32 out ----------------

__global__ __launch_bounds__(256) void k_spmm40_lsm(const unsigned short* __restrict__ S,
                                                    const int* __restrict__ rp,
                                                    const uint2* __restrict__ cw,
                                                    const float* __restrict__ bias,
                                                    float* __restrict__ out,
                                                    int n) {
    int wid  = threadIdx.x >> 6;
    int lane = threadIdx.x & 63;
    int node = blockIdx.x * 4 + wid;
    if (node >= n) return;
    int s = rp[node], e = rp[node + 1];
    float a0 = 0.f, a1 = 0.f, a2 = 0.f, a3 = 0.f;
    int i = s;
    bool act = lane < NCLASS;
    for (; i + 4 <= e; i += 4) {
        uint2 e0 = cw[i], e1 = cw[i + 1], e2 = cw[i + 2], e3 = cw[i + 3];
        if (act) {
            float v0 = bf2f(S[(size_t)e0.x * NCLASS + lane]);
            float v1 = bf2f(S[(size_t)e1.x * NCLASS + lane]);
            float v2 = bf2f(S[(size_t)e2.x * NCLASS + lane]);
            float v3 = bf2f(S[(size_t)e3.x * NCLASS + lane]);
            a0 = fmaf(__uint_as_float(e0.y), v0, a0);
            a1 = fmaf(__uint_as_float(e1.y), v1, a1);
            a2 = fmaf(__uint_as_float(e2.y), v2, a2);
            a3 = fmaf(__uint_as_float(e3.y), v3, a3);
        }
    }
    for (; i < e; i++) {
        uint2 e0 = cw[i];
        if (act) a0 = fmaf(__uint_as_float(e0.y), bf2f(S[(size_t)e0.x * NCLASS + lane]), a0);
    }
    float acc = (a0 + a1) + (a2 + a3);
    float logit = act ? acc + bias[lane] : -INFINITY;
    float m = logit;
#pragma unroll
    for (int o = 32; o >= 1; o >>= 1) m = fmaxf(m, __shfl_xor(m, o, 64));
    float ex = act ? expf(logit - m) : 0.f;
    float ssum = ex;
#pragma unroll
    for (int o = 32; o >= 1; o >>= 1) ssum += __shfl_xor(ssum, o, 64);
    if (act) {
        float r = logit - m - logf(ssum);
        __builtin_nontemporal_store(r, out + (size_t)node * NCLASS + lane);
    }
}

// ---------------- launch ----------------

extern "C" void kernel_launch(void* const* d_in, const int* in_sizes, int n_in,
                              void* d_out, int out_size, void* d_ws, size_t ws_size,
                              hipStream_t stream) {
    const float* x  = (const float*)d_in[0];
    const int* row  = (const int*)d_in[1];
    const int* col  = (const int*)d_in[2];
    const float* ew = (const float*)d_in[3];
    const float* W1 = (const float*)d_in[4];
    const float* b1 = (const float*)d_in[5];
    const float* W2 = (const float*)d_in[6];
    const float* b2 = (const float*)d_in[7];
    const float* W3 = (const float*)d_in[8];
    const float* b3 = (const float*)d_in[9];
    const float* W4 = (const float*)d_in[10];
    const float* b4 = (const float*)d_in[11];
    float* out = (float*)d_out;

    const int Nn = in_sizes[0] / NFEAT;
    const int E  = in_sizes[1];
    const int NB = (Nn + 255) / 256;
    const int Mpad = (Nn + 63) & ~63;

    char* ws = (char*)d_ws;
    size_t off = 0;
    auto alloc = [&](size_t bytes) {
        size_t o = off;
        off = (off + bytes + 255) & ~(size_t)255;
        return o;
    };
    int*   row_ptr  = (int*)(ws + alloc((size_t)(Nn + 1) * 4));
    int*   counts   = (int*)(ws + alloc((size_t)Nn * 4));       // also reused as cursor
    int*   partials = (int*)(ws + alloc((size_t)NB * 4));
    uint2* csr_cw   = (uint2*)(ws + alloc((size_t)E * 8));
    unsigned short* Sb  = (unsigned short*)(ws + alloc((size_t)Mpad * NHID * 2));
    unsigned short* Hb  = (unsigned short*)(ws + alloc((size_t)Mpad * NHID * 2));
    unsigned short* S4b = (unsigned short*)(ws + alloc((size_t)Mpad * NCLASS * 2));
    unsigned short* Wt1 = (unsigned short*)(ws + alloc((size_t)128 * 512 * 2));
    unsigned short* Wt2 = (unsigned short*)(ws + alloc((size_t)128 * 128 * 2));
    unsigned short* Wt3 = (unsigned short*)(ws + alloc((size_t)128 * 128 * 2));
    unsigned short* Wt4 = (unsigned short*)(ws + alloc((size_t)48 * 128 * 2));

    // ---- weight prep ----
    k_prep_w<<<(128 * 512 + 255) / 256, 256, 0, stream>>>(W1, Wt1, NFEAT, NHID, 128, 512);
    k_prep_w<<<(128 * 128 + 255) / 256, 256, 0, stream>>>(W2, Wt2, NHID, NHID, 128, 128);
    k_prep_w<<<(128 * 128 + 255) / 256, 256, 0, stream>>>(W3, Wt3, NHID, NHID, 128, 128);
    k_prep_w<<<(48 * 128 + 255) / 256, 256, 0, stream>>>(W4, Wt4, NHID, NCLASS, 48, 128);

    // ---- CSR build ----
    (void)hipMemsetAsync(counts, 0, (size_t)Nn * 4, stream);
    k_hist<<<(E + 255) / 256, 256, 0, stream>>>(row, E, counts);
    k_block_sum<<<NB, 256, 0, stream>>>(counts, Nn, partials);
    k_scan_partials<<<1, 512, 0, stream>>>(partials, NB);
    k_scan_counts<<<NB, 256, 0, stream>>>(counts, partials, row_ptr, Nn);
    k_scatter<<<(E + 255) / 256, 256, 0, stream>>>(row, col, ew, E, row_ptr, counts, csr_cw);

    const int gblocks = Mpad / 64;
    const int spmm_blocks = (Nn + 3) / 4;

    // layer 1: x @ W1 -> Sb ; spmm+b1+relu -> Hb
    k_gemm_mfma<true, 128, 128, 128><<<gblocks, 256, 0, stream>>>(x, Wt1, Sb, Nn, NFEAT, 512);
    k_spmm128<<<spmm_blocks, 256, 0, stream>>>(Sb, row_ptr, csr_cw, b1, Hb, Nn, 1);
    // layer 2
    k_gemm_mfma<false, 128, 128, 128><<<gblocks, 256, 0, stream>>>(Hb, Wt2, Sb, Nn, NHID, NHID);
    k_spmm128<<<spmm_blocks, 256, 0, stream>>>(Sb, row_ptr, csr_cw, b2, Hb, Nn, 1);
    // layer 3
    k_gemm_mfma<false, 128, 128, 128><<<gblocks, 256, 0, stream>>>(Hb, Wt3, Sb, Nn, NHID, NHID);
    k_spmm128<<<spmm_blocks, 256, 0, stream>>>(Sb, row_ptr, csr_cw, b3, Hb, Nn, 1);
    // layer 4: Hb @ W4 -> S4b[N,40] ; spmm+b4+log_softmax -> out (fp32)
    k_gemm_mfma<false, 48, 40, 40><<<gblocks, 256, 0, stream>>>(Hb, Wt4, S4b, Nn, NHID, NHID);
    k_spmm40_lsm<<<spmm_blocks, 256, 0, stream>>>(S4b, row_ptr, csr_cw, b4, out, Nn);
}

// Round 6
// 860.120 us; speedup vs baseline: 1.0473x; 1.0473x over previous
//
#include <hip/hip_runtime.h>
#include <cstdint>
#include <cstddef>

#define NFEAT 500
#define NHID  128
#define NCLASS 40

typedef __attribute__((ext_vector_type(8))) short bf16x8;
typedef __attribute__((ext_vector_type(4))) float f32x4;

__device__ __forceinline__ unsigned short f2bf(float f) {
    union { float f; unsigned u; } v; v.f = f;
    unsigned u = v.u;
    unsigned r = u + 0x7FFF + ((u >> 16) & 1);   // round-to-nearest-even
    return (unsigned short)(r >> 16);
}
__device__ __forceinline__ float bf2f(unsigned short h) {
    union { unsigned u; float f; } v; v.u = ((unsigned)h) << 16; return v.f;
}

// ---------------- CSR construction ----------------

__global__ void k_hist(const int* __restrict__ row, int E, int* __restrict__ counts) {
    int i = blockIdx.x * 256 + threadIdx.x;
    if (i < E) atomicAdd(&counts[row[i]], 1);
}

__global__ void k_block_sum(const int* __restrict__ counts, int n, int* __restrict__ partials) {
    __shared__ int tmp[256];
    int i = blockIdx.x * 256 + threadIdx.x;
    tmp[threadIdx.x] = (i < n) ? counts[i] : 0;
    __syncthreads();
    for (int o = 128; o > 0; o >>= 1) {
        if (threadIdx.x < o) tmp[threadIdx.x] += tmp[threadIdx.x + o];
        __syncthreads();
    }
    if (threadIdx.x == 0) partials[blockIdx.x] = tmp[0];
}

__global__ void k_scan_partials(int* __restrict__ partials, int nb) {
    __shared__ int tmp[512];
    int t = threadIdx.x;
    int v = (t < nb) ? partials[t] : 0;
    tmp[t] = v;
    __syncthreads();
    for (int o = 1; o < 512; o <<= 1) {
        int add = (t >= o) ? tmp[t - o] : 0;
        __syncthreads();
        tmp[t] += add;
        __syncthreads();
    }
    if (t < nb) partials[t] = tmp[t] - v;   // exclusive
}

// also zeroes counts for reuse as cursor
__global__ void k_scan_counts(int* __restrict__ counts, const int* __restrict__ partials,
                              int* __restrict__ row_ptr, int n) {
    __shared__ int tmp[256];
    int t = threadIdx.x;
    int i = blockIdx.x * 256 + t;
    int v = (i < n) ? counts[i] : 0;
    tmp[t] = v;
    __syncthreads();
    for (int o = 1; o < 256; o <<= 1) {
        int add = (t >= o) ? tmp[t - o] : 0;
        __syncthreads();
        tmp[t] += add;
        __syncthreads();
    }
    int incl = tmp[t];
    int base = partials[blockIdx.x];
    if (i < n) {
        row_ptr[i] = base + incl - v;
        counts[i] = 0;
    }
    if (i == n - 1) row_ptr[n] = base + incl;
}

__global__ void k_scatter(const int* __restrict__ row, const int* __restrict__ col,
                          const float* __restrict__ w, int E,
                          const int* __restrict__ row_ptr, int* __restrict__ cursor,
                          uint2* __restrict__ csr_cw) {
    int i = blockIdx.x * 256 + threadIdx.x;
    if (i < E) {
        int r = row[i];
        int p = row_ptr[r] + atomicAdd(&cursor[r], 1);
        csr_cw[p] = make_uint2((unsigned)col[i], __float_as_uint(w[i]));
    }
}

// ---------------- weight prep: W[K][N] fp32 -> Wt[Nt][Kpad] bf16 (transposed, zero-padded) ----------------

__global__ void k_prep_w(const float* __restrict__ W, unsigned short* __restrict__ Wt,
                         int K, int Norig, int Nt, int Kpad) {
    int idx = blockIdx.x * 256 + threadIdx.x;
    if (idx >= Nt * Kpad) return;
    int n = idx / Kpad, k = idx % Kpad;
    unsigned short v = 0;
    if (k < K && n < Norig) v = f2bf(W[(size_t)k * Norig + n]);
    Wt[idx] = v;
}

// ---------------- MFMA GEMM: C[M][CPITCH] = A[M][K] @ Wt^T, bf16 out, fp32 acc ----------------
// BM=128, BK=32, 256 threads (4 waves). A: LDS double-buffered with register prefetch,
// ONE barrier per K-iter. B: direct global->fragment loads (Wt is [n][k], exactly MFMA
// B-layout; 128 KB -> L2-resident). BN=128: wave grid 2x2 (64x64/wave, TM=4 TN=4).
// BN=48: 4x1 (32x48/wave, TM=2 TN=3). Buffers padded to Mpad rows; only fp32-A guards M.

template<bool AFP32, int BN, int CN, int CPITCH>
__global__ __launch_bounds__(256) void k_gemm_mfma(const void* __restrict__ Ain,
                                                   const unsigned short* __restrict__ Wt,
                                                   unsigned short* __restrict__ C,
                                                   int M, int K, int Kpad) {
    constexpr int P  = 40;                     // LDS pitch (ushorts) = 80 B
    constexpr int NW = (BN == 128) ? 2 : 1;
    constexpr int MW = 4 / NW;
    constexpr int TM = 128 / (MW * 16);
    constexpr int TN = BN / (NW * 16);
    __shared__ unsigned short As[2][128][P];   // 20.0 KB total

    const int t = threadIdx.x;
    const int lane = t & 63;
    const int w = t >> 6;
    const int wm = w / NW, wn = w % NW;
    const int mbase = blockIdx.x * 128;
    const int l15 = lane & 15, quad = lane >> 4;

    const float* Af = (const float*)Ain;
    const unsigned short* Ab = (const unsigned short*)Ain;

    f32x4 acc[TM][TN];
#pragma unroll
    for (int mi = 0; mi < TM; mi++)
#pragma unroll
        for (int ni = 0; ni < TN; ni++)
            acc[mi][ni] = (f32x4){0.f, 0.f, 0.f, 0.f};

    // A staging registers (prefetch)
    float4 ra_f[4];   // fp32 path: 16 floats/thread
    uint4  ra_b[2];   // bf16 path: 2x16B/thread

    auto loadA = [&](int k0) {
        if (AFP32) {
#pragma unroll
            for (int p = 0; p < 4; p++) {
                int idx = p * 256 + t;
                int m = idx >> 3, ch = idx & 7;
                int gm = mbase + m, gk = k0 + ch * 4;
                float4 v = make_float4(0.f, 0.f, 0.f, 0.f);
                if (gm < M && gk + 4 <= K) v = *(const float4*)(Af + (size_t)gm * K + gk);
                ra_f[p] = v;
            }
        } else {
#pragma unroll
            for (int p = 0; p < 2; p++) {
                int idx = p * 256 + t;
                int m = idx >> 2, ch = idx & 3;
                ra_b[p] = *(const uint4*)(Ab + (size_t)(mbase + m) * Kpad + k0 + ch * 8);
            }
        }
    };
    auto storeLDS = [&](int buf) {
        if (AFP32) {
#pragma unroll
            for (int p = 0; p < 4; p++) {
                int idx = p * 256 + t;
                int m = idx >> 3, ch = idx & 7;
                float4 v = ra_f[p];
                unsigned long long pk = (unsigned long long)f2bf(v.x)
                                      | ((unsigned long long)f2bf(v.y) << 16)
                                      | ((unsigned long long)f2bf(v.z) << 32)
                                      | ((unsigned long long)f2bf(v.w) << 48);
                *(unsigned long long*)&As[buf][m][ch * 4] = pk;
            }
        } else {
#pragma unroll
            for (int p = 0; p < 2; p++) {
                int idx = p * 256 + t;
                int m = idx >> 2, ch = idx & 3;
                *(uint4*)&As[buf][m][ch * 8] = ra_b[p];
            }
        }
    };

    const int nIter = Kpad >> 5;
    loadA(0);
    storeLDS(0);
    __syncthreads();

    for (int it = 0; it < nIter; it++) {
        const int cur = it & 1;
        const int k0 = it << 5;
        const bool more = (it + 1) < nIter;
        if (more) loadA(k0 + 32);              // global loads in flight over compute

        // B fragments: direct global (L2-hot)
        bf16x8 bfr[TN];
#pragma unroll
        for (int ni = 0; ni < TN; ni++)
            bfr[ni] = *(const bf16x8*)(Wt + (size_t)(wn * (TN * 16) + ni * 16 + l15) * Kpad + k0 + quad * 8);

        bf16x8 afr[TM];
#pragma unroll
        for (int mi = 0; mi < TM; mi++)
            afr[mi] = *(const bf16x8*)&As[cur][wm * (TM * 16) + mi * 16 + l15][quad * 8];

#pragma unroll
        for (int mi = 0; mi < TM; mi++)
#pragma unroll
            for (int ni = 0; ni < TN; ni++)
                acc[mi][ni] = __builtin_amdgcn_mfma_f32_16x16x32_bf16(afr[mi], bfr[ni], acc[mi][ni], 0, 0, 0);

        if (more) {
            storeLDS(cur ^ 1);                 // waits on prefetch, writes other buffer
            __syncthreads();                   // ONE barrier per iter
        }
    }

    // epilogue: C/D layout col=lane&15, row=quad*4+reg ; rows padded, no M guard
#pragma unroll
    for (int mi = 0; mi < TM; mi++) {
#pragma unroll
        for (int r = 0; r < 4; r++) {
            int gm = mbase + wm * (TM * 16) + mi * 16 + quad * 4 + r;
#pragma unroll
            for (int ni = 0; ni < TN; ni++) {
                int gn = wn * (TN * 16) + ni * 16 + l15;
                if (gn < CN) C[(size_t)gm * CPITCH + gn] = f2bf(acc[mi][ni][r]);
            }
        }
    }
}

// ---------------- SpMM (width 128, bf16) + bias + optional ReLU ----------------

__global__ __launch_bounds__(256) void k_spmm128(const unsigned short* __restrict__ S,
                                                 const int* __restrict__ rp,
                                                 const uint2* __restrict__ cw,
                                                 const float* __restrict__ bias,
                                                 unsigned short* __restrict__ out,
                                                 int n, int do_relu) {
    int wid  = threadIdx.x >> 6;
    int lane = threadIdx.x & 63;
    int node = blockIdx.x * 4 + wid;
    if (node >= n) return;
    int s = rp[node], e = rp[node + 1];
    float a0x = 0.f, a0y = 0.f, a1x = 0.f, a1y = 0.f;
    float a2x = 0.f, a2y = 0.f, a3x = 0.f, a3y = 0.f;
    int i = s;
    for (; i + 4 <= e; i += 4) {
        uint2 e0 = cw[i], e1 = cw[i + 1], e2 = cw[i + 2], e3 = cw[i + 3];
        unsigned v0 = ((const unsigned*)(S + (size_t)e0.x * NHID))[lane];
        unsigned v1 = ((const unsigned*)(S + (size_t)e1.x * NHID))[lane];
        unsigned v2 = ((const unsigned*)(S + (size_t)e2.x * NHID))[lane];
        unsigned v3 = ((const unsigned*)(S + (size_t)e3.x * NHID))[lane];
        float w0 = __uint_as_float(e0.y), w1 = __uint_as_float(e1.y);
        float w2 = __uint_as_float(e2.y), w3 = __uint_as_float(e3.y);
        a0x = fmaf(w0, bf2f((unsigned short)v0), a0x); a0y = fmaf(w0, bf2f((unsigned short)(v0 >> 16)), a0y);
        a1x = fmaf(w1, bf2f((unsigned short)v1), a1x); a1y = fmaf(w1, bf2f((unsigned short)(v1 >> 16)), a1y);
        a2x = fmaf(w2, bf2f((unsigned short)v2), a2x); a2y = fmaf(w2, bf2f((unsigned short)(v2 >> 16)), a2y);
        a3x = fmaf(w3, bf2f((unsigned short)v3), a3x); a3y = fmaf(w3, bf2f((unsigned short)(v3 >> 16)), a3y);
    }
    for (; i < e; i++) {
        uint2 e0 = cw[i];
        unsigned v0 = ((const unsigned*)(S + (size_t)e0.x * NHID))[lane];
        float w0 = __uint_as_float(e0.y);
        a0x = fmaf(w0, bf2f((unsigned short)v0), a0x); a0y = fmaf(w0, bf2f((unsigned short)(v0 >> 16)), a0y);
    }
    float ax = (a0x + a1x) + (a2x + a3x) + bias[lane * 2];
    float ay = (a0y + a1y) + (a2y + a3y) + bias[lane * 2 + 1];
    if (do_relu) {
        ax = fmaxf(ax, 0.f);
        ay = fmaxf(ay, 0.f);
    }
    unsigned o = (unsigned)f2bf(ax) | ((unsigned)f2bf(ay) << 16);
    __builtin_nontemporal_store(o, (unsigned*)(out + (size_t)node * NHID) + lane);
}

// ---------------- SpMM (width 40, bf16 pitch 40) + bias + log_softmax -> fp32 out ----------------

__global__ __launch_bounds__(256) void k_spmm40_lsm(const unsigned short* __restrict__ S,
                                                    const int* __restrict__ rp,
                                                    const uint2* __restrict__ cw,
                                                    const float* __restrict__ bias,
                                                    float* __restrict__ out,
                                                    int n) {
    int wid  = threadIdx.x >> 6;
    int lane = threadIdx.x & 63;
    int node = blockIdx.x * 4 + wid;
    if (node >= n) return;
    int s = rp[node], e = rp[node + 1];
    float a0 = 0.f, a1 = 0.f, a2 = 0.f, a3 = 0.f;
    int i = s;
    bool act = lane < NCLASS;
    for (; i + 4 <= e; i += 4) {
        uint2 e0 = cw[i], e1 = cw[i + 1], e2 = cw[i + 2], e3 = cw[i + 3];
        if (act) {
            float v0 = bf2f(S[(size_t)e0.x * NCLASS + lane]);
            float v1 = bf2f(S[(size_t)e1.x * NCLASS + lane]);
            float v2 = bf2f(S[(size_t)e2.x * NCLASS + lane]);
            float v3 = bf2f(S[(size_t)e3.x * NCLASS + lane]);
            a0 = fmaf(__uint_as_float(e0.y), v0, a0);
            a1 = fmaf(__uint_as_float(e1.y), v1, a1);
            a2 = fmaf(__uint_as_float(e2.y), v2, a2);
            a3 = fmaf(__uint_as_float(e3.y), v3, a3);
        }
    }
    for (; i < e; i++) {
        uint2 e0 = cw[i];
        if (act) a0 = fmaf(__uint_as_float(e0.y), bf2f(S[(size_t)e0.x * NCLASS + lane]), a0);
    }
    float acc = (a0 + a1) + (a2 + a3);
    float logit = act ? acc + bias[lane] : -INFINITY;
    float m = logit;
#pragma unroll
    for (int o = 32; o >= 1; o >>= 1) m = fmaxf(m, __shfl_xor(m, o, 64));
    float ex = act ? expf(logit - m) : 0.f;
    float ssum = ex;
#pragma unroll
    for (int o = 32; o >= 1; o >>= 1) ssum += __shfl_xor(ssum, o, 64);
    if (act) {
        float r = logit - m - logf(ssum);
        __builtin_nontemporal_store(r, out + (size_t)node * NCLASS + lane);
    }
}

// ---------------- launch ----------------

extern "C" void kernel_launch(void* const* d_in, const int* in_sizes, int n_in,
                              void* d_out, int out_size, void* d_ws, size_t ws_size,
                              hipStream_t stream) {
    const float* x  = (const float*)d_in[0];
    const int* row  = (const int*)d_in[1];
    const int* col  = (const int*)d_in[2];
    const float* ew = (const float*)d_in[3];
    const float* W1 = (const float*)d_in[4];
    const float* b1 = (const float*)d_in[5];
    const float* W2 = (const float*)d_in[6];
    const float* b2 = (const float*)d_in[7];
    const float* W3 = (const float*)d_in[8];
    const float* b3 = (const float*)d_in[9];
    const float* W4 = (const float*)d_in[10];
    const float* b4 = (const float*)d_in[11];
    float* out = (float*)d_out;

    const int Nn = in_sizes[0] / NFEAT;
    const int E  = in_sizes[1];
    const int NB = (Nn + 255) / 256;
    const int Mpad = (Nn + 127) & ~127;

    char* ws = (char*)d_ws;
    size_t off = 0;
    auto alloc = [&](size_t bytes) {
        size_t o = off;
        off = (off + bytes + 255) & ~(size_t)255;
        return o;
    };
    int*   row_ptr  = (int*)(ws + alloc((size_t)(Nn + 1) * 4));
    int*   counts   = (int*)(ws + alloc((size_t)Nn * 4));       // also reused as cursor
    int*   partials = (int*)(ws + alloc((size_t)NB * 4));
    uint2* csr_cw   = (uint2*)(ws + alloc((size_t)E * 8));
    unsigned short* Sb  = (unsigned short*)(ws + alloc((size_t)Mpad * NHID * 2));
    unsigned short* Hb  = (unsigned short*)(ws + alloc((size_t)Mpad * NHID * 2));
    unsigned short* S4b = (unsigned short*)(ws + alloc((size_t)Mpad * NCLASS * 2));
    unsigned short* Wt1 = (unsigned short*)(ws + alloc((size_t)128 * 512 * 2));
    unsigned short* Wt2 = (unsigned short*)(ws + alloc((size_t)128 * 128 * 2));
    unsigned short* Wt3 = (unsigned short*)(ws + alloc((size_t)128 * 128 * 2));
    unsigned short* Wt4 = (unsigned short*)(ws + alloc((size_t)48 * 128 * 2));

    // ---- weight prep ----
    k_prep_w<<<(128 * 512 + 255) / 256, 256, 0, stream>>>(W1, Wt1, NFEAT, NHID, 128, 512);
    k_prep_w<<<(128 * 128 + 255) / 256, 256, 0, stream>>>(W2, Wt2, NHID, NHID, 128, 128);
    k_prep_w<<<(128 * 128 + 255) / 256, 256, 0, stream>>>(W3, Wt3, NHID, NHID, 128, 128);
    k_prep_w<<<(48 * 128 + 255) / 256, 256, 0, stream>>>(W4, Wt4, NHID, NCLASS, 48, 128);

    // ---- CSR build ----
    (void)hipMemsetAsync(counts, 0, (size_t)Nn * 4, stream);
    k_hist<<<(E + 255) / 256, 256, 0, stream>>>(row, E, counts);
    k_block_sum<<<NB, 256, 0, stream>>>(counts, Nn, partials);
    k_scan_partials<<<1, 512, 0, stream>>>(partials, NB);
    k_scan_counts<<<NB, 256, 0, stream>>>(counts, partials, row_ptr, Nn);
    k_scatter<<<(E + 255) / 256, 256, 0, stream>>>(row, col, ew, E, row_ptr, counts, csr_cw);

    const int gblocks = Mpad / 128;
    const int spmm_blocks = (Nn + 3) / 4;

    // layer 1: x @ W1 -> Sb ; spmm+b1+relu -> Hb
    k_gemm_mfma<true, 128, 128, 128><<<gblocks, 256, 0, stream>>>(x, Wt1, Sb, Nn, NFEAT, 512);
    k_spmm128<<<spmm_blocks, 256, 0, stream>>>(Sb, row_ptr, csr_cw, b1, Hb, Nn, 1);
    // layer 2
    k_gemm_mfma<false, 128, 128, 128><<<gblocks, 256, 0, stream>>>(Hb, Wt2, Sb, Nn, NHID, NHID);
    k_spmm128<<<spmm_blocks, 256, 0, stream>>>(Sb, row_ptr, csr_cw, b2, Hb, Nn, 1);
    // layer 3
    k_gemm_mfma<false, 128, 128, 128><<<gblocks, 256, 0, stream>>>(Hb, Wt3, Sb, Nn, NHID, NHID);
    k_spmm128<<<spmm_blocks, 256, 0, stream>>>(Sb, row_ptr, csr_cw, b3, Hb, Nn, 1);
    // layer 4: Hb @ W4 -> S4b[N,40] ; spmm+b4+log_softmax -> out (fp32)
    k_gemm_mfma<false, 48, 40, 40><<<gblocks, 256, 0, stream>>>(Hb, Wt4, S4b, Nn, NHID, NHID);
    k_spmm40_lsm<<<spmm_blocks, 256, 0, stream>>>(S4b, row_ptr, csr_cw, b4, out, Nn);
}